// Round 1
// baseline (1071.340 us; speedup 1.0000x reference)
//
#include <hip/hip_runtime.h>
#include <hip/hip_fp16.h>

// ---- problem constants (S=4096, H=1024, F=4096, E=8, cap=1280) ----
#define S_TOK 4096
#define HDIM  1024
#define FDIM  4096
#define NEXP  8
#define CAPV  1280

typedef _Float16 half8  __attribute__((ext_vector_type(8)));
typedef _Float16 half4v __attribute__((ext_vector_type(4)));
typedef _Float16 half2v __attribute__((ext_vector_type(2)));
typedef float    floatx4 __attribute__((ext_vector_type(4)));

// async global->LDS, 16B per lane; lds base must be wave-uniform
__device__ __forceinline__ void gld_lds16(const _Float16* g, _Float16* l) {
  __builtin_amdgcn_global_load_lds(
      (const __attribute__((address_space(1))) unsigned int*)g,
      (__attribute__((address_space(3))) unsigned int*)l, 16, 0, 0);
}

// ---------------- transpose + fp32->fp16: W[K,N] -> Wt[N,K], batched over E ----------------
__global__ __launch_bounds__(256) void transpose_convert(
    const float* __restrict__ W, _Float16* __restrict__ Wt, int Kd, int Nd)
{
  __shared__ float tile[64][65];
  const size_t ebase = (size_t)blockIdx.z * Kd * Nd;
  const float* Wp = W + ebase;
  _Float16* Wtp = Wt + ebase;
  const int n0 = blockIdx.x * 64, k0 = blockIdx.y * 64;
  const int tid = threadIdx.x;
#pragma unroll
  for (int r = 0; r < 16; ++r) {
    int idx = r * 256 + tid;
    int kk = idx >> 6, nn = idx & 63;
    tile[kk][nn] = Wp[(size_t)(k0 + kk) * Nd + (n0 + nn)];
  }
  __syncthreads();
#pragma unroll
  for (int r = 0; r < 8; ++r) {
    int idx = (r * 256 + tid) * 2;
    int kk = idx & 63, nn = idx >> 6;
    half2v hv;
    hv[0] = (_Float16)tile[kk][nn];
    hv[1] = (_Float16)tile[kk + 1][nn];
    *(half2v*)(Wtp + (size_t)(n0 + nn) * Kd + (k0 + kk)) = hv;
  }
}

// ---------------- router: logits, softmax, top-2 (one wave per token) ----------------
__global__ __launch_bounds__(256) void router_kernel(
    const float* __restrict__ tokens, const float* __restrict__ gw,
    int* __restrict__ top1, int* __restrict__ top2,
    float* __restrict__ w1, float* __restrict__ w2)
{
  const int wave = threadIdx.x >> 6, lane = threadIdx.x & 63;
  const int s = blockIdx.x * 4 + wave;
  const float* trow = tokens + (size_t)s * HDIM;
  float acc[8] = {0.f,0.f,0.f,0.f,0.f,0.f,0.f,0.f};
  for (int h = lane; h < HDIM; h += 64) {
    float t = trow[h];
    const float4* g = (const float4*)(gw + h * 8);
    float4 g0 = g[0], g1 = g[1];
    acc[0] += t * g0.x; acc[1] += t * g0.y; acc[2] += t * g0.z; acc[3] += t * g0.w;
    acc[4] += t * g1.x; acc[5] += t * g1.y; acc[6] += t * g1.z; acc[7] += t * g1.w;
  }
#pragma unroll
  for (int e = 0; e < 8; ++e) {
    acc[e] += __shfl_down(acc[e], 32);
    acc[e] += __shfl_down(acc[e], 16);
    acc[e] += __shfl_down(acc[e], 8);
    acc[e] += __shfl_down(acc[e], 4);
    acc[e] += __shfl_down(acc[e], 2);
    acc[e] += __shfl_down(acc[e], 1);
  }
  if (lane == 0) {
    float m = acc[0];
#pragma unroll
    for (int e = 1; e < 8; ++e) m = fmaxf(m, acc[e]);
    float sum = 0.f;
#pragma unroll
    for (int e = 0; e < 8; ++e) sum += expf(acc[e] - m);
    int t1 = 0; float b1 = acc[0];
#pragma unroll
    for (int e = 1; e < 8; ++e) if (acc[e] > b1) { b1 = acc[e]; t1 = e; }
    int t2 = -1; float b2 = -1e30f;
#pragma unroll
    for (int e = 0; e < 8; ++e) if (e != t1 && acc[e] > b2) { b2 = acc[e]; t2 = e; }
    top1[s] = t1; top2[s] = t2;
    w1[s] = expf(b1 - m) / sum;
    w2[s] = expf(b2 - m) / sum;
  }
}

// ---------------- scan: ranks with capacity, slot->token map (single block, ordered) ----------------
__global__ __launch_bounds__(256) void scan_kernel(
    const int* __restrict__ top1, const int* __restrict__ top2,
    float* __restrict__ w1, float* __restrict__ w2,
    int* __restrict__ r1, int* __restrict__ r2, int* __restrict__ src)
{
  __shared__ int lds[256][16];
  const int tid = threadIdx.x;
  for (int i = tid; i < NEXP * CAPV; i += 256) src[i] = -1;
  int c1[8] = {0,0,0,0,0,0,0,0}, c2[8] = {0,0,0,0,0,0,0,0};
  const int base = tid * 16;
  for (int j = 0; j < 16; ++j) {
    int e1 = top1[base + j], e2 = top2[base + j];
#pragma unroll
    for (int e = 0; e < 8; ++e) { c1[e] += (e1 == e); c2[e] += (e2 == e); }
  }
#pragma unroll
  for (int e = 0; e < 8; ++e) { lds[tid][e] = c1[e]; lds[tid][8 + e] = c2[e]; }
  __syncthreads();
  for (int off = 1; off < 256; off <<= 1) {
    int vals[16];
#pragma unroll
    for (int i = 0; i < 16; ++i) vals[i] = (tid >= off) ? lds[tid - off][i] : 0;
    __syncthreads();
#pragma unroll
    for (int i = 0; i < 16; ++i) lds[tid][i] += vals[i];
    __syncthreads();
  }
  int b1[8], b2[8], tot1[8];
#pragma unroll
  for (int e = 0; e < 8; ++e) {
    b1[e] = lds[tid][e] - c1[e];
    b2[e] = lds[tid][8 + e] - c2[e];
    tot1[e] = lds[255][e];
  }
  for (int j = 0; j < 16; ++j) {
    int s = base + j;
    int e1 = top1[s];
    int r = b1[e1]++;
    bool k1 = (r < CAPV);
    r1[s] = k1 ? r : 0;
    if (!k1) w1[s] = 0.f; else src[e1 * CAPV + r] = s;
    int e2 = top2[s];
    int rr = (b2[e2]++) + tot1[e2];   // rank2 offset by pre-capacity top1 total
    bool k2 = (rr < CAPV);
    r2[s] = k2 ? rr : 0;
    if (!k2) w2[s] = 0.f; else src[e2 * CAPV + rr] = s;
  }
}

// ---------------- gather: build dispatch fp16 [E*CAP, H]; empty slots -> zeros ----------------
__global__ __launch_bounds__(128) void gather_kernel(
    const float* __restrict__ tokens, const int* __restrict__ src,
    _Float16* __restrict__ disp)
{
  const int slot = blockIdx.x;
  const int s = src[slot];
  _Float16* drow = disp + (size_t)slot * HDIM;
  const int t = threadIdx.x;  // 128 threads, 8 elems each
  if (s < 0) {
    uint4 z = make_uint4(0u, 0u, 0u, 0u);
    ((uint4*)drow)[t] = z;
  } else {
    const float4* trow = (const float4*)(tokens + (size_t)s * HDIM);
    float4 a = trow[2 * t], b = trow[2 * t + 1];
    half8 h;
    h[0] = (_Float16)a.x; h[1] = (_Float16)a.y; h[2] = (_Float16)a.z; h[3] = (_Float16)a.w;
    h[4] = (_Float16)b.x; h[5] = (_Float16)b.y; h[6] = (_Float16)b.z; h[7] = (_Float16)b.w;
    *(half8*)(drow + t * 8) = h;
  }
}

// ---------------- GEMM: C[M,N] fp16 = A[M,K] @ Bt[N,K]^T, batched over E ----------------
// 128x128 tile, BK=64, 4 waves (2x2 of 64x64), 16x16x32 f16 MFMA,
// global_load_lds(16B) staging, XOR-swizzled LDS (chunk p = c ^ (row&7)).
__global__ __launch_bounds__(256) void gemm_f16(
    const _Float16* __restrict__ A, const _Float16* __restrict__ B,
    _Float16* __restrict__ C, int N, int K,
    long long sA, long long sB, long long sC)
{
  __shared__ _Float16 As[128 * 64];
  __shared__ _Float16 Bs[128 * 64];
  A += (size_t)blockIdx.z * sA;
  B += (size_t)blockIdx.z * sB;
  C += (size_t)blockIdx.z * sC;
  const int bm = blockIdx.y * 128, bn = blockIdx.x * 128;
  const int tid = threadIdx.x, wave = tid >> 6, lane = tid & 63;
  const int wm = (wave & 1) << 6, wn = (wave >> 1) << 6;

  // staging pointers: inst j covers LDS rows (wave*4+j)*8 .. +8
  const _Float16* gA[4]; const _Float16* gB[4];
  _Float16 *lA[4], *lB[4];
#pragma unroll
  for (int j = 0; j < 4; ++j) {
    int row = ((wave << 2) + j) * 8 + (lane >> 3);
    int c = (lane & 7) ^ (row & 7);          // global chunk for stored pos lane&7
    gA[j] = A + (size_t)(bm + row) * K + c * 8;
    gB[j] = B + (size_t)(bn + row) * K + c * 8;
    lA[j] = As + ((wave << 2) + j) * 512;    // wave-uniform base (halves)
    lB[j] = Bs + ((wave << 2) + j) * 512;
  }

  floatx4 acc[4][4] = {};

  const int kTiles = K >> 6;
  for (int kt = 0; kt < kTiles; ++kt) {
#pragma unroll
    for (int j = 0; j < 4; ++j) {
      gld_lds16(gA[j], lA[j]);
      gld_lds16(gB[j], lB[j]);
      gA[j] += 64; gB[j] += 64;
    }
    __syncthreads();
#pragma unroll
    for (int ks = 0; ks < 2; ++ks) {
      half8 af[4], bf[4];
#pragma unroll
      for (int mt = 0; mt < 4; ++mt) {
        int row = wm + mt * 16 + (lane & 15);
        int cc = (ks << 2) + (lane >> 4);
        int p = cc ^ (row & 7);
        af[mt] = *(const half8*)(As + row * 64 + p * 8);
      }
#pragma unroll
      for (int nt = 0; nt < 4; ++nt) {
        int row = wn + nt * 16 + (lane & 15);
        int cc = (ks << 2) + (lane >> 4);
        int p = cc ^ (row & 7);
        bf[nt] = *(const half8*)(Bs + row * 64 + p * 8);
      }
#pragma unroll
      for (int mt = 0; mt < 4; ++mt)
#pragma unroll
        for (int nt = 0; nt < 4; ++nt)
          acc[mt][nt] = __builtin_amdgcn_mfma_f32_16x16x32_f16(af[mt], bf[nt], acc[mt][nt], 0, 0, 0);
    }
    __syncthreads();
  }

  // epilogue: C/D layout col=lane&15, row=(lane>>4)*4+r
  const int q = lane >> 4, cl = lane & 15;
#pragma unroll
  for (int mt = 0; mt < 4; ++mt)
#pragma unroll
    for (int r = 0; r < 4; ++r) {
      int grow = bm + wm + mt * 16 + q * 4 + r;
      size_t rowoff = (size_t)grow * N + bn + wn + cl;
#pragma unroll
      for (int nt = 0; nt < 4; ++nt)
        C[rowoff + nt * 16] = (_Float16)acc[mt][nt][r];
    }
}

// ---------------- SwiGLU: U <- x1 * silu(x2) * U (in place), x1/x2 from G ----------------
__global__ __launch_bounds__(256) void act_kernel(
    const _Float16* __restrict__ G, _Float16* __restrict__ U)
{
  const size_t idx = ((size_t)blockIdx.x * 256 + threadIdx.x) * 8;
  const size_t ec = idx >> 12;            // / FDIM
  const int f = (int)(idx & (FDIM - 1));
  half8 x1 = *(const half8*)(G + ec * (2 * FDIM) + f);
  half8 x2 = *(const half8*)(G + ec * (2 * FDIM) + FDIM + f);
  half8 u  = *(half8*)(U + idx);
  half8 out;
#pragma unroll
  for (int i = 0; i < 8; ++i) {
    float a = (float)x1[i], b = (float)x2[i], c = (float)u[i];
    float silu = b / (1.f + expf(-b));
    out[i] = (_Float16)(a * silu * c);
  }
  *(half8*)(U + idx) = out;
}

// ---------------- combine: out[s] = w1*eo[e1,r1] + w2*eo[e2,r2] ----------------
__global__ __launch_bounds__(256) void combine_kernel(
    const _Float16* __restrict__ eo,
    const int* __restrict__ top1, const int* __restrict__ top2,
    const float* __restrict__ w1, const float* __restrict__ w2,
    const int* __restrict__ r1, const int* __restrict__ r2,
    float* __restrict__ out)
{
  const int s = blockIdx.x;
  const int e1 = top1[s], e2 = top2[s];
  const float a = w1[s], b = w2[s];
  const int q1 = r1[s], q2 = r2[s];
  const _Float16* row1 = eo + ((size_t)e1 * CAPV + q1) * HDIM;
  const _Float16* row2 = eo + ((size_t)e2 * CAPV + q2) * HDIM;
  const int t = threadIdx.x;  // 256 threads, 4 elems each
  half4v h1 = *(const half4v*)(row1 + t * 4);
  half4v h2 = *(const half4v*)(row2 + t * 4);
  float4 v;
  v.x = a * (float)h1[0] + b * (float)h2[0];
  v.y = a * (float)h1[1] + b * (float)h2[1];
  v.z = a * (float)h1[2] + b * (float)h2[2];
  v.w = a * (float)h1[3] + b * (float)h2[3];
  *(float4*)(out + (size_t)s * HDIM + t * 4) = v;
}

// ---------------- launch ----------------
extern "C" void kernel_launch(void* const* d_in, const int* in_sizes, int n_in,
                              void* d_out, int out_size, void* d_ws, size_t ws_size,
                              hipStream_t stream) {
  const float* hs     = (const float*)d_in[0];  // [S,H]
  const float* gate_w = (const float*)d_in[1];  // [H,E]
  const float* w_gate = (const float*)d_in[2];  // [E,H,2F]
  const float* w_up   = (const float*)d_in[3];  // [E,H,F]
  const float* w_down = (const float*)d_in[4];  // [E,F,H]
  float* out = (float*)d_out;

  char* ws = (char*)d_ws;
  size_t off = 0;
  _Float16* WT_GATE = (_Float16*)(ws + off); off += (size_t)NEXP * 2 * FDIM * HDIM * 2;  // 134.2MB
  _Float16* WT_UP   = (_Float16*)(ws + off); off += (size_t)NEXP * FDIM * HDIM * 2;      // 67.1MB
  _Float16* WT_DOWN = (_Float16*)(ws + off); off += (size_t)NEXP * HDIM * FDIM * 2;      // 67.1MB
  _Float16* DISP    = (_Float16*)(ws + off); off += (size_t)NEXP * CAPV * HDIM * 2;      // 21.0MB
  _Float16* G       = (_Float16*)(ws + off); off += (size_t)NEXP * CAPV * 2 * FDIM * 2;  // 167.8MB
  _Float16* U       = (_Float16*)(ws + off); off += (size_t)NEXP * CAPV * FDIM * 2;      // 83.9MB
  _Float16* EO      = (_Float16*)(ws + off); off += (size_t)NEXP * CAPV * HDIM * 2;      // 21.0MB
  int*   TOP1 = (int*)(ws + off);   off += S_TOK * 4;
  int*   TOP2 = (int*)(ws + off);   off += S_TOK * 4;
  int*   R1   = (int*)(ws + off);   off += S_TOK * 4;
  int*   R2   = (int*)(ws + off);   off += S_TOK * 4;
  float* W1   = (float*)(ws + off); off += S_TOK * 4;
  float* W2   = (float*)(ws + off); off += S_TOK * 4;
  int*   SRC  = (int*)(ws + off);   off += NEXP * CAPV * 4;

  // weights -> fp16 transposed [N][K]
  transpose_convert<<<dim3(2 * FDIM / 64, HDIM / 64, NEXP), 256, 0, stream>>>(w_gate, WT_GATE, HDIM, 2 * FDIM);
  transpose_convert<<<dim3(FDIM / 64, HDIM / 64, NEXP), 256, 0, stream>>>(w_up, WT_UP, HDIM, FDIM);
  transpose_convert<<<dim3(HDIM / 64, FDIM / 64, NEXP), 256, 0, stream>>>(w_down, WT_DOWN, FDIM, HDIM);

  // routing
  router_kernel<<<S_TOK / 4, 256, 0, stream>>>(hs, gate_w, TOP1, TOP2, W1, W2);
  scan_kernel<<<1, 256, 0, stream>>>(TOP1, TOP2, W1, W2, R1, R2, SRC);
  gather_kernel<<<NEXP * CAPV, 128, 0, stream>>>(hs, SRC, DISP);

  // expert MLP
  gemm_f16<<<dim3(2 * FDIM / 128, CAPV / 128, NEXP), 256, 0, stream>>>(
      DISP, WT_GATE, G, 2 * FDIM, HDIM,
      (long long)CAPV * HDIM, (long long)2 * FDIM * HDIM, (long long)CAPV * 2 * FDIM);
  gemm_f16<<<dim3(FDIM / 128, CAPV / 128, NEXP), 256, 0, stream>>>(
      DISP, WT_UP, U, FDIM, HDIM,
      (long long)CAPV * HDIM, (long long)FDIM * HDIM, (long long)CAPV * FDIM);
  act_kernel<<<(NEXP * CAPV * FDIM) / (256 * 8), 256, 0, stream>>>(G, U);
  gemm_f16<<<dim3(HDIM / 128, CAPV / 128, NEXP), 256, 0, stream>>>(
      U, WT_DOWN, EO, HDIM, FDIM,
      (long long)CAPV * FDIM, (long long)HDIM * FDIM, (long long)CAPV * HDIM);

  // combine
  combine_kernel<<<S_TOK, 256, 0, stream>>>(EO, TOP1, TOP2, W1, W2, R1, R2, out);
}

// Round 2
// 1014.543 us; speedup vs baseline: 1.0560x; 1.0560x over previous
//
#include <hip/hip_runtime.h>
#include <hip/hip_fp16.h>

// ---- problem constants (S=4096, H=1024, F=4096, E=8, cap=1280) ----
#define S_TOK 4096
#define HDIM  1024
#define FDIM  4096
#define NEXP  8
#define CAPV  1280

typedef _Float16 half8  __attribute__((ext_vector_type(8)));
typedef _Float16 half4v __attribute__((ext_vector_type(4)));
typedef float    floatx4 __attribute__((ext_vector_type(4)));

// async global->LDS, 16B per lane; lds base must be wave-uniform
__device__ __forceinline__ void gld_lds16(const _Float16* g, _Float16* l) {
  __builtin_amdgcn_global_load_lds(
      (const __attribute__((address_space(1))) unsigned int*)g,
      (__attribute__((address_space(3))) unsigned int*)l, 16, 0, 0);
}

// ---------------- transpose + fp32->fp16: W[K,N] -> Wt[N,K], 16B/lane both dirs ----------------
__global__ __launch_bounds__(256) void transpose_convert(
    const float* __restrict__ W, _Float16* __restrict__ Wt, int Kd, int Nd)
{
  __shared__ float tile[64][65];
  const size_t ebase = (size_t)blockIdx.z * Kd * Nd;
  const float* Wp = W + ebase;
  _Float16* Wtp = Wt + ebase;
  const int n0 = blockIdx.x * 64, k0 = blockIdx.y * 64;
  const int tid = threadIdx.x;
#pragma unroll
  for (int r = 0; r < 4; ++r) {
    int l = r * 256 + tid;           // [0,1024)
    int n4 = l & 15, kk = l >> 4;    // 16 float4 along N, 64 rows
    float4 v = *(const float4*)(Wp + (size_t)(k0 + kk) * Nd + n0 + n4 * 4);
    tile[kk][n4 * 4 + 0] = v.x;
    tile[kk][n4 * 4 + 1] = v.y;
    tile[kk][n4 * 4 + 2] = v.z;
    tile[kk][n4 * 4 + 3] = v.w;
  }
  __syncthreads();
#pragma unroll
  for (int r = 0; r < 2; ++r) {
    int l = r * 256 + tid;           // [0,512)
    int kk8 = l & 7, nn = l >> 3;    // 8 half8 along K, 64 rows
    half8 h;
#pragma unroll
    for (int j = 0; j < 8; ++j) h[j] = (_Float16)tile[kk8 * 8 + j][nn];
    *(half8*)(Wtp + (size_t)(n0 + nn) * Kd + k0 + kk8 * 8) = h;
  }
}

// ---------------- router: logits, softmax, top-2 (one wave per token) ----------------
__global__ __launch_bounds__(256) void router_kernel(
    const float* __restrict__ tokens, const float* __restrict__ gw,
    int* __restrict__ top1, int* __restrict__ top2,
    float* __restrict__ w1, float* __restrict__ w2)
{
  const int wave = threadIdx.x >> 6, lane = threadIdx.x & 63;
  const int s = blockIdx.x * 4 + wave;
  const float* trow = tokens + (size_t)s * HDIM;
  float acc[8] = {0.f,0.f,0.f,0.f,0.f,0.f,0.f,0.f};
  for (int h = lane; h < HDIM; h += 64) {
    float t = trow[h];
    const float4* g = (const float4*)(gw + h * 8);
    float4 g0 = g[0], g1 = g[1];
    acc[0] += t * g0.x; acc[1] += t * g0.y; acc[2] += t * g0.z; acc[3] += t * g0.w;
    acc[4] += t * g1.x; acc[5] += t * g1.y; acc[6] += t * g1.z; acc[7] += t * g1.w;
  }
#pragma unroll
  for (int e = 0; e < 8; ++e) {
    acc[e] += __shfl_down(acc[e], 32);
    acc[e] += __shfl_down(acc[e], 16);
    acc[e] += __shfl_down(acc[e], 8);
    acc[e] += __shfl_down(acc[e], 4);
    acc[e] += __shfl_down(acc[e], 2);
    acc[e] += __shfl_down(acc[e], 1);
  }
  if (lane == 0) {
    float m = acc[0];
#pragma unroll
    for (int e = 1; e < 8; ++e) m = fmaxf(m, acc[e]);
    float sum = 0.f;
#pragma unroll
    for (int e = 0; e < 8; ++e) sum += expf(acc[e] - m);
    int t1 = 0; float b1 = acc[0];
#pragma unroll
    for (int e = 1; e < 8; ++e) if (acc[e] > b1) { b1 = acc[e]; t1 = e; }
    int t2 = -1; float b2 = -1e30f;
#pragma unroll
    for (int e = 0; e < 8; ++e) if (e != t1 && acc[e] > b2) { b2 = acc[e]; t2 = e; }
    top1[s] = t1; top2[s] = t2;
    w1[s] = expf(b1 - m) / sum;
    w2[s] = expf(b2 - m) / sum;
  }
}

// ---------------- scan: ranks with capacity, slot->token map (single block, ordered) ----------------
__global__ __launch_bounds__(256) void scan_kernel(
    const int* __restrict__ top1, const int* __restrict__ top2,
    float* __restrict__ w1, float* __restrict__ w2,
    int* __restrict__ r1, int* __restrict__ r2, int* __restrict__ src)
{
  __shared__ int lds[256][16];
  const int tid = threadIdx.x;
  for (int i = tid; i < NEXP * CAPV; i += 256) src[i] = -1;
  int c1[8] = {0,0,0,0,0,0,0,0}, c2[8] = {0,0,0,0,0,0,0,0};
  const int base = tid * 16;
  for (int j = 0; j < 16; ++j) {
    int e1 = top1[base + j], e2 = top2[base + j];
#pragma unroll
    for (int e = 0; e < 8; ++e) { c1[e] += (e1 == e); c2[e] += (e2 == e); }
  }
#pragma unroll
  for (int e = 0; e < 8; ++e) { lds[tid][e] = c1[e]; lds[tid][8 + e] = c2[e]; }
  __syncthreads();
  for (int off = 1; off < 256; off <<= 1) {
    int vals[16];
#pragma unroll
    for (int i = 0; i < 16; ++i) vals[i] = (tid >= off) ? lds[tid - off][i] : 0;
    __syncthreads();
#pragma unroll
    for (int i = 0; i < 16; ++i) lds[tid][i] += vals[i];
    __syncthreads();
  }
  int b1[8], b2[8], tot1[8];
#pragma unroll
  for (int e = 0; e < 8; ++e) {
    b1[e] = lds[tid][e] - c1[e];
    b2[e] = lds[tid][8 + e] - c2[e];
    tot1[e] = lds[255][e];
  }
  for (int j = 0; j < 16; ++j) {
    int s = base + j;
    int e1 = top1[s];
    int r = b1[e1]++;
    bool k1 = (r < CAPV);
    r1[s] = k1 ? r : 0;
    if (!k1) w1[s] = 0.f; else src[e1 * CAPV + r] = s;
    int e2 = top2[s];
    int rr = (b2[e2]++) + tot1[e2];   // rank2 offset by pre-capacity top1 total
    bool k2 = (rr < CAPV);
    r2[s] = k2 ? rr : 0;
    if (!k2) w2[s] = 0.f; else src[e2 * CAPV + rr] = s;
  }
}

// ---------------- gather: build dispatch fp16 [E*CAP, H]; empty slots -> zeros ----------------
__global__ __launch_bounds__(256) void gather_kernel(
    const float* __restrict__ tokens, const int* __restrict__ src,
    _Float16* __restrict__ disp)
{
  const int slot = blockIdx.x * 2 + (threadIdx.x >> 7);
  const int s = src[slot];
  _Float16* drow = disp + (size_t)slot * HDIM;
  const int t = threadIdx.x & 127;  // 128 threads per slot, 8 elems each
  if (s < 0) {
    uint4 z = make_uint4(0u, 0u, 0u, 0u);
    ((uint4*)drow)[t] = z;
  } else {
    const float4* trow = (const float4*)(tokens + (size_t)s * HDIM);
    float4 a = trow[2 * t], b = trow[2 * t + 1];
    half8 h;
    h[0] = (_Float16)a.x; h[1] = (_Float16)a.y; h[2] = (_Float16)a.z; h[3] = (_Float16)a.w;
    h[4] = (_Float16)b.x; h[5] = (_Float16)b.y; h[6] = (_Float16)b.z; h[7] = (_Float16)b.w;
    *(half8*)(drow + t * 8) = h;
  }
}

// ---------------- fused gate+up+SwiGLU GEMM ----------------
// Block: 128 rows (c) x 64 cols (f) of THREE outputs x1/x2/u; epilogue computes
// act = x1 * silu(x2) * u and writes ACT only (G/U never materialized).
// 4 waves 2x2: wave region 64(m) x 32(n); 16x16x32 f16 MFMA; XOR-swizzled LDS.
__global__ __launch_bounds__(256) void gemm_gateup_act(
    const _Float16* __restrict__ A, const _Float16* __restrict__ WG,
    const _Float16* __restrict__ WU, _Float16* __restrict__ ACT)
{
  __shared__ _Float16 As[128 * 64];
  __shared__ _Float16 Bs[3][64 * 64];
  const int e = blockIdx.z;
  A += (size_t)e * CAPV * HDIM;
  ACT += (size_t)e * CAPV * FDIM;
  const _Float16* B0 = WG + (size_t)e * 2 * FDIM * HDIM;          // x1 rows
  const _Float16* B1 = B0 + (size_t)FDIM * HDIM;                  // x2 rows
  const _Float16* B2 = WU + (size_t)e * FDIM * HDIM;              // u rows
  const int bm = blockIdx.y * 128, f0 = blockIdx.x * 64;
  const int tid = threadIdx.x, wave = tid >> 6, lane = tid & 63;
  const int wm = (wave & 1) << 6, wn = (wave >> 1) << 5;

  const int subrow = lane >> 3;                  // row within 8-row group
  const int cch = (lane & 7) ^ subrow;           // global chunk for stored pos lane&7

  // A staging: 4 insts, rows j*32 + wave*8 + subrow
  const _Float16* gA[4]; _Float16* lA[4];
#pragma unroll
  for (int j = 0; j < 4; ++j) {
    int row = j * 32 + wave * 8 + subrow;
    gA[j] = A + (size_t)(bm + row) * HDIM + cch * 8;
    lA[j] = As + (j * 32 + wave * 8) * 64;
  }
  // B staging: per output 2 insts, rows j*32 + wave*8 + subrow (64-row tiles)
  const _Float16* gB[3][2]; _Float16* lB[3][2];
#pragma unroll
  for (int j = 0; j < 2; ++j) {
    int row = j * 32 + wave * 8 + subrow;
    gB[0][j] = B0 + (size_t)(f0 + row) * HDIM + cch * 8;
    gB[1][j] = B1 + (size_t)(f0 + row) * HDIM + cch * 8;
    gB[2][j] = B2 + (size_t)(f0 + row) * HDIM + cch * 8;
#pragma unroll
    for (int o = 0; o < 3; ++o) lB[o][j] = Bs[o] + (j * 32 + wave * 8) * 64;
  }

  floatx4 acc[3][4][2] = {};

  for (int kt = 0; kt < HDIM / 64; ++kt) {
#pragma unroll
    for (int j = 0; j < 4; ++j) { gld_lds16(gA[j], lA[j]); gA[j] += 64; }
#pragma unroll
    for (int j = 0; j < 2; ++j)
#pragma unroll
      for (int o = 0; o < 3; ++o) { gld_lds16(gB[o][j], lB[o][j]); gB[o][j] += 64; }
    __syncthreads();
#pragma unroll
    for (int ks = 0; ks < 2; ++ks) {
      const int cc = (ks << 2) + (lane >> 4);
      half8 af[4], bf[3][2];
#pragma unroll
      for (int mt = 0; mt < 4; ++mt) {
        int row = wm + mt * 16 + (lane & 15);
        int p = cc ^ (row & 7);
        af[mt] = *(const half8*)(As + row * 64 + p * 8);
      }
#pragma unroll
      for (int nt = 0; nt < 2; ++nt) {
        int row = wn + nt * 16 + (lane & 15);
        int p = cc ^ (row & 7);
#pragma unroll
        for (int o = 0; o < 3; ++o)
          bf[o][nt] = *(const half8*)(Bs[o] + row * 64 + p * 8);
      }
#pragma unroll
      for (int o = 0; o < 3; ++o)
#pragma unroll
        for (int mt = 0; mt < 4; ++mt)
#pragma unroll
          for (int nt = 0; nt < 2; ++nt)
            acc[o][mt][nt] = __builtin_amdgcn_mfma_f32_16x16x32_f16(af[mt], bf[o][nt], acc[o][mt][nt], 0, 0, 0);
    }
    __syncthreads();
  }

  // epilogue: C/D layout col=lane&15, row=(lane>>4)*4+r; act = x1*silu(x2)*u
  const int q = lane >> 4, cl = lane & 15;
#pragma unroll
  for (int mt = 0; mt < 4; ++mt)
#pragma unroll
    for (int r = 0; r < 4; ++r) {
      int grow = bm + wm + mt * 16 + q * 4 + r;
      size_t rowoff = (size_t)grow * FDIM + f0 + wn + cl;
#pragma unroll
      for (int nt = 0; nt < 2; ++nt) {
        float x1 = acc[0][mt][nt][r];
        float x2 = acc[1][mt][nt][r];
        float u  = acc[2][mt][nt][r];
        float sw = x2 / (1.f + __expf(-x2));
        ACT[rowoff + nt * 16] = (_Float16)(x1 * sw * u);
      }
    }
}

// ---------------- GEMM: C[M,N] fp16 = A[M,K] @ Bt[N,K]^T, batched over E (down proj) ----------------
__global__ __launch_bounds__(256) void gemm_f16(
    const _Float16* __restrict__ A, const _Float16* __restrict__ B,
    _Float16* __restrict__ C, int N, int K,
    long long sA, long long sB, long long sC)
{
  __shared__ _Float16 As[128 * 64];
  __shared__ _Float16 Bs[128 * 64];
  A += (size_t)blockIdx.z * sA;
  B += (size_t)blockIdx.z * sB;
  C += (size_t)blockIdx.z * sC;
  const int bm = blockIdx.y * 128, bn = blockIdx.x * 128;
  const int tid = threadIdx.x, wave = tid >> 6, lane = tid & 63;
  const int wm = (wave & 1) << 6, wn = (wave >> 1) << 6;

  const _Float16* gA[4]; const _Float16* gB[4];
  _Float16 *lA[4], *lB[4];
#pragma unroll
  for (int j = 0; j < 4; ++j) {
    int row = ((wave << 2) + j) * 8 + (lane >> 3);
    int c = (lane & 7) ^ (row & 7);
    gA[j] = A + (size_t)(bm + row) * K + c * 8;
    gB[j] = B + (size_t)(bn + row) * K + c * 8;
    lA[j] = As + ((wave << 2) + j) * 512;
    lB[j] = Bs + ((wave << 2) + j) * 512;
  }

  floatx4 acc[4][4] = {};

  const int kTiles = K >> 6;
  for (int kt = 0; kt < kTiles; ++kt) {
#pragma unroll
    for (int j = 0; j < 4; ++j) {
      gld_lds16(gA[j], lA[j]);
      gld_lds16(gB[j], lB[j]);
      gA[j] += 64; gB[j] += 64;
    }
    __syncthreads();
#pragma unroll
    for (int ks = 0; ks < 2; ++ks) {
      half8 af[4], bf[4];
#pragma unroll
      for (int mt = 0; mt < 4; ++mt) {
        int row = wm + mt * 16 + (lane & 15);
        int p = ((ks << 2) + (lane >> 4)) ^ (row & 7);
        af[mt] = *(const half8*)(As + row * 64 + p * 8);
      }
#pragma unroll
      for (int nt = 0; nt < 4; ++nt) {
        int row = wn + nt * 16 + (lane & 15);
        int p = ((ks << 2) + (lane >> 4)) ^ (row & 7);
        bf[nt] = *(const half8*)(Bs + row * 64 + p * 8);
      }
#pragma unroll
      for (int mt = 0; mt < 4; ++mt)
#pragma unroll
        for (int nt = 0; nt < 4; ++nt)
          acc[mt][nt] = __builtin_amdgcn_mfma_f32_16x16x32_f16(af[mt], bf[nt], acc[mt][nt], 0, 0, 0);
    }
    __syncthreads();
  }

  const int q = lane >> 4, cl = lane & 15;
#pragma unroll
  for (int mt = 0; mt < 4; ++mt)
#pragma unroll
    for (int r = 0; r < 4; ++r) {
      int grow = bm + wm + mt * 16 + q * 4 + r;
      size_t rowoff = (size_t)grow * N + bn + wn + cl;
#pragma unroll
      for (int nt = 0; nt < 4; ++nt)
        C[rowoff + nt * 16] = (_Float16)acc[mt][nt][r];
    }
}

// ---------------- combine: out[s] = w1*eo[e1,r1] + w2*eo[e2,r2] ----------------
__global__ __launch_bounds__(256) void combine_kernel(
    const _Float16* __restrict__ eo,
    const int* __restrict__ top1, const int* __restrict__ top2,
    const float* __restrict__ w1, const float* __restrict__ w2,
    const int* __restrict__ r1, const int* __restrict__ r2,
    float* __restrict__ out)
{
  const int s = blockIdx.x;
  const int e1 = top1[s], e2 = top2[s];
  const float a = w1[s], b = w2[s];
  const int q1 = r1[s], q2 = r2[s];
  const _Float16* row1 = eo + ((size_t)e1 * CAPV + q1) * HDIM;
  const _Float16* row2 = eo + ((size_t)e2 * CAPV + q2) * HDIM;
  const int t = threadIdx.x;
  half4v h1 = *(const half4v*)(row1 + t * 4);
  half4v h2 = *(const half4v*)(row2 + t * 4);
  float4 v;
  v.x = a * (float)h1[0] + b * (float)h2[0];
  v.y = a * (float)h1[1] + b * (float)h2[1];
  v.z = a * (float)h1[2] + b * (float)h2[2];
  v.w = a * (float)h1[3] + b * (float)h2[3];
  *(float4*)(out + (size_t)s * HDIM + t * 4) = v;
}

// ---------------- launch ----------------
extern "C" void kernel_launch(void* const* d_in, const int* in_sizes, int n_in,
                              void* d_out, int out_size, void* d_ws, size_t ws_size,
                              hipStream_t stream) {
  const float* hs     = (const float*)d_in[0];  // [S,H]
  const float* gate_w = (const float*)d_in[1];  // [H,E]
  const float* w_gate = (const float*)d_in[2];  // [E,H,2F]
  const float* w_up   = (const float*)d_in[3];  // [E,H,F]
  const float* w_down = (const float*)d_in[4];  // [E,F,H]
  float* out = (float*)d_out;

  char* ws = (char*)d_ws;
  size_t off = 0;
  _Float16* WT_GATE = (_Float16*)(ws + off); off += (size_t)NEXP * 2 * FDIM * HDIM * 2;  // 134.2MB
  _Float16* WT_UP   = (_Float16*)(ws + off); off += (size_t)NEXP * FDIM * HDIM * 2;      // 67.1MB
  _Float16* WT_DOWN = (_Float16*)(ws + off); off += (size_t)NEXP * HDIM * FDIM * 2;      // 67.1MB
  _Float16* DISP    = (_Float16*)(ws + off); off += (size_t)NEXP * CAPV * HDIM * 2;      // 21.0MB
  _Float16* ACT     = (_Float16*)(ws + off); off += (size_t)NEXP * CAPV * FDIM * 2;      // 83.9MB
  _Float16* EO      = (_Float16*)(ws + off); off += (size_t)NEXP * CAPV * HDIM * 2;      // 21.0MB
  int*   TOP1 = (int*)(ws + off);   off += S_TOK * 4;
  int*   TOP2 = (int*)(ws + off);   off += S_TOK * 4;
  int*   R1   = (int*)(ws + off);   off += S_TOK * 4;
  int*   R2   = (int*)(ws + off);   off += S_TOK * 4;
  float* W1   = (float*)(ws + off); off += S_TOK * 4;
  float* W2   = (float*)(ws + off); off += S_TOK * 4;
  int*   SRC  = (int*)(ws + off);   off += NEXP * CAPV * 4;

  // weights -> fp16 transposed [N][K]
  transpose_convert<<<dim3(2 * FDIM / 64, HDIM / 64, NEXP), 256, 0, stream>>>(w_gate, WT_GATE, HDIM, 2 * FDIM);
  transpose_convert<<<dim3(FDIM / 64, HDIM / 64, NEXP), 256, 0, stream>>>(w_up, WT_UP, HDIM, FDIM);
  transpose_convert<<<dim3(HDIM / 64, FDIM / 64, NEXP), 256, 0, stream>>>(w_down, WT_DOWN, FDIM, HDIM);

  // routing
  router_kernel<<<S_TOK / 4, 256, 0, stream>>>(hs, gate_w, TOP1, TOP2, W1, W2);
  scan_kernel<<<1, 256, 0, stream>>>(TOP1, TOP2, W1, W2, R1, R2, SRC);
  gather_kernel<<<NEXP * CAPV / 2, 256, 0, stream>>>(hs, SRC, DISP);

  // fused gate+up+SwiGLU, then down proj
  gemm_gateup_act<<<dim3(FDIM / 64, CAPV / 128, NEXP), 256, 0, stream>>>(
      DISP, WT_GATE, WT_UP, ACT);
  gemm_f16<<<dim3(HDIM / 128, CAPV / 128, NEXP), 256, 0, stream>>>(
      ACT, WT_DOWN, EO, HDIM, FDIM,
      (long long)CAPV * FDIM, (long long)HDIM * FDIM, (long long)CAPV * HDIM);

  // combine
  combine_kernel<<<S_TOK, 256, 0, stream>>>(EO, TOP1, TOP2, W1, W2, R1, R2, out);
}